// Round 24
// baseline (157.847 us; speedup 1.0000x reference)
//
#include <hip/hip_runtime.h>
#include <hip/hip_bf16.h>

typedef unsigned short u16;
typedef __bf16 bf16x8 __attribute__((ext_vector_type(8)));
typedef u16 u16x8 __attribute__((ext_vector_type(8)));
typedef float f32x4 __attribute__((ext_vector_type(4)));

__device__ __forceinline__ float bf2f(u16 u) {
    return __uint_as_float(((unsigned)u) << 16);
}
__device__ __forceinline__ u16 f2bf(float f) {
    unsigned u = __float_as_uint(f);
    unsigned r = (u + 0x7fffu + ((u >> 16) & 1u)) >> 16;
    return (u16)r;
}

// async global->LDS, 16B per lane. dst is wave-uniform base; HW adds lane*16.
__device__ __forceinline__ void gl_lds16(const u16* g, u16* l) {
    __builtin_amdgcn_global_load_lds(
        (const __attribute__((address_space(1))) void*)g,
        (__attribute__((address_space(3))) void*)l, 16, 0, 0);
}

// ---------------- fused prep: x f32->bf16 convert + 3 weight transposes ----------------
__global__ __launch_bounds__(256) void prep(const float* __restrict__ x,
                                            const float* __restrict__ Wv,
                                            const float* __restrict__ Wa,
                                            const float* __restrict__ Wo,
                                            u16* __restrict__ xb,
                                            u16* __restrict__ WvTv,
                                            u16* __restrict__ WaT,
                                            u16* __restrict__ WoT) {
    __shared__ float tile[64][65];
    int blk = blockIdx.x;
    if (blk < 10280) {
        int i = (blk * 256 + threadIdx.x) * 8;
        float4 a = *(const float4*)&x[i];
        float4 b = *(const float4*)&x[i + 4];
        u16x8 o;
        o[0] = f2bf(a.x); o[1] = f2bf(a.y); o[2] = f2bf(a.z); o[3] = f2bf(a.w);
        o[4] = f2bf(b.x); o[5] = f2bf(b.y); o[6] = f2bf(b.z); o[7] = f2bf(b.w);
        *(u16x8*)&xb[i] = o;
        return;
    }
    blk -= 10280;
    const float* W; u16* WT; int N, stride, coff;
    if (blk < 64)       { W = Wv; WT = WvTv; N = 512;  stride = 1536; coff = 1024; }
    else if (blk < 256) { W = Wa; WT = WaT;  N = 1536; stride = 1536; coff = 0; blk -= 64; }
    else                { W = Wo; WT = WoT;  N = 512;  stride = 512;  coff = 0; blk -= 256; }
    const int nt = N >> 6;
    const int k0 = (blk / nt) << 6;
    const int n0 = (blk % nt) << 6;
    for (int i = threadIdx.x; i < 4096; i += 256) {
        int r = i >> 6, c = i & 63;
        tile[r][c] = W[(size_t)(k0 + r) * stride + coff + n0 + c];
    }
    __syncthreads();
    for (int i = threadIdx.x; i < 4096; i += 256) {
        int r = i >> 6, c = i & 63;
        WT[(size_t)(n0 + r) * 512 + k0 + c] = f2bf(tile[c][r]);
    }
}

// ---------------- small m97-style GEMM ----------
// MODE 0: row r->r (clamp). MODE 2: row r->r*257 (clamp).
// OUTF 0: bf16 out. OUTF 2: f32 out + bias, out row map r*257.
template <int MODE, int OUTF>
__global__ __launch_bounds__(256) void gemm_k(const u16* __restrict__ A,
                                              const u16* __restrict__ Bt,
                                              void* __restrict__ Cv,
                                              const float* __restrict__ bias,
                                              int M, int N, int K) {
    __shared__ u16 As[128][64];
    __shared__ u16 Bs[128][64];
    const int t = threadIdx.x;
    const int bn0 = blockIdx.x * 128;
    const int bm0 = blockIdx.y * 128;
    const int wave = t >> 6, lane = t & 63;
    const int wm = (wave >> 1) * 64, wn = (wave & 1) * 64;
    const int lr = lane & 15, lh = lane >> 4;
    const int srow = wave * 8 + (lane >> 3);
    const int scol = (lane & 7) * 8;

    f32x4 acc[4][4] = {};

    for (int kt = 0; kt < K; kt += 64) {
        __syncthreads();
#pragma unroll
        for (int i = 0; i < 4; i++) {
            int row = i * 32 + srow;
            int r = bm0 + row;
            long g;
            if (MODE == 0) g = (r < M) ? (long)r : 0l;
            else           g = (r < M) ? (long)r * 257 : 0l;
            gl_lds16(&A[g * K + kt + scol], &As[0][0] + i * 2048 + wave * 512);
            long nr = bn0 + row;
            gl_lds16(&Bt[nr * K + kt + scol], &Bs[0][0] + i * 2048 + wave * 512);
        }
        __syncthreads();
#pragma unroll
        for (int kk = 0; kk < 2; kk++) {
            bf16x8 af[4], bfr[4];
#pragma unroll
            for (int mi = 0; mi < 4; mi++)
                af[mi] = *(const bf16x8*)&As[wm + mi * 16 + lr][kk * 32 + lh * 8];
#pragma unroll
            for (int ni = 0; ni < 4; ni++)
                bfr[ni] = *(const bf16x8*)&Bs[wn + ni * 16 + lr][kk * 32 + lh * 8];
#pragma unroll
            for (int mi = 0; mi < 4; mi++)
#pragma unroll
                for (int ni = 0; ni < 4; ni++)
                    acc[mi][ni] = __builtin_amdgcn_mfma_f32_16x16x32_bf16(
                        af[mi], bfr[ni], acc[mi][ni], 0, 0, 0);
        }
    }

#pragma unroll
    for (int mi = 0; mi < 4; mi++)
#pragma unroll
        for (int ni = 0; ni < 4; ni++)
#pragma unroll
            for (int r2 = 0; r2 < 4; r2++) {
                int m = bm0 + wm + mi * 16 + lh * 4 + r2;
                if (m < M) {
                    int nc = bn0 + wn + ni * 16 + lr;
                    float v = acc[mi][ni][r2];
                    if (OUTF == 2) ((float*)Cv)[(size_t)m * 257 * N + nc] = v + bias[nc];
                    else           ((u16*)Cv)[(size_t)m * N + nc] = f2bf(v);
                }
            }
}

// ---------------- gemm_vs: fused vv-projection + scores, pipelined 256-tile ----------------
// Grid 480 (1-D, XCD-swizzled): wgid -> my = wgid/3 (= bt, 256 A-rows), sec = wgid%3.
// sec 0,1: vv tile, B = WvTv, cols sec*256..+256  -> vv bf16.
// sec 2:   scores, B = wcomb[b] (rows 0..79 real; rest feed only discarded cols).
// 16x16x32 MFMA (round-23 lesson: 32x32x16 fragment reads defeat the row&7
// swizzle — rows are bank-wrap-aligned so lanes {l,l+8,l+16,l+24} collide
// 4-way, 3.9e6 conflicts, +2us. Swizzle is shape-coupled; 16x16 measures 0.)
__global__ __launch_bounds__(1024) void gemm_vs(const u16* __restrict__ A,
                                                const u16* __restrict__ WvTv,
                                                const u16* __restrict__ wcomb,
                                                u16* __restrict__ vv,
                                                float* __restrict__ pglob,
                                                float* __restrict__ vascore) {
    __shared__ u16 As[2][256][64];
    __shared__ u16 Bs[2][256][64];
    const int t = threadIdx.x;
    const int nwg = gridDim.x;                 // 480, %8==0
    const int orig = blockIdx.x;
    const int qc = nwg >> 3;
    const int xcd = orig & 7, slot = orig >> 3;
    const int wgid = xcd * qc + slot;
    const int my = wgid / 3, sec = wgid % 3;   // my = bt
    const int bm0 = my * 256;
    const int bt = my, b = bt / 5, t5 = bt - b * 5;
    const int bn0 = (sec < 2) ? sec * 256 : 0;
    const u16* Bt = (sec < 2) ? WvTv : (wcomb + (size_t)b * 256 * 512);
    const int wave = t >> 6, lane = t & 63;
    const int wm = (wave >> 2) * 64, wn = (wave & 3) * 64;
    const int lr = lane & 15, lh = lane >> 4;
    const int xr = (lr & 7) << 3;              // read-side swizzle (row&7 == lr&7)
    u16* AsF = &As[0][0][0];
    u16* BsF = &Bs[0][0][0];

    const int gsa = ((lane & 7) ^ (lane >> 3)) * 8;
    auto stage = [&](int buf, int kt_) {
        const int kc = kt_ * 64;
#pragma unroll
        for (int j = 0; j < 2; j++) {
            int c0 = j * 1024 + wave * 64;
            int row = (c0 + lane) >> 3;
            int r = bm0 + row;
            long ga = (long)(r >> 8) * 257 + (r & 255) + 1;   // V rows of x
            gl_lds16(&A[ga * 512 + kc + gsa], AsF + buf * 16384 + c0 * 8);
            gl_lds16(&Bt[(long)(bn0 + row) * 512 + kc + gsa], BsF + buf * 16384 + c0 * 8);
        }
    };

    f32x4 acc[4][4] = {};

    stage(0, 0);
    __builtin_amdgcn_sched_barrier(0);
    stage(1, 1);
    __builtin_amdgcn_sched_barrier(0);
    asm volatile("s_waitcnt vmcnt(0)" ::: "memory");
    __builtin_amdgcn_s_barrier();
    __builtin_amdgcn_sched_barrier(0);

    int cur = 0;
    for (int kt = 0; kt < 8; kt++) {
        __builtin_amdgcn_s_setprio(1);
#pragma unroll
        for (int kk = 0; kk < 2; kk++) {
            bf16x8 af[4], bfr[4];
#pragma unroll
            for (int mi = 0; mi < 4; mi++)
                af[mi] = *(const bf16x8*)&As[cur][wm + mi * 16 + lr][(kk * 32 + lh * 8) ^ xr];
#pragma unroll
            for (int ni = 0; ni < 4; ni++)
                bfr[ni] = *(const bf16x8*)&Bs[cur][wn + ni * 16 + lr][(kk * 32 + lh * 8) ^ xr];
#pragma unroll
            for (int mi = 0; mi < 4; mi++)
#pragma unroll
                for (int ni = 0; ni < 4; ni++)
                    acc[mi][ni] = __builtin_amdgcn_mfma_f32_16x16x32_bf16(
                        af[mi], bfr[ni], acc[mi][ni], 0, 0, 0);
        }
        __builtin_amdgcn_s_setprio(0);
        if (kt == 7) break;
        __builtin_amdgcn_sched_barrier(0);
        __builtin_amdgcn_s_barrier();
        __builtin_amdgcn_sched_barrier(0);
        if (kt + 2 < 8) {
            stage(cur, kt + 2);
            __builtin_amdgcn_sched_barrier(0);
            asm volatile("s_waitcnt vmcnt(4)" ::: "memory");
        } else {
            asm volatile("s_waitcnt vmcnt(0)" ::: "memory");
        }
        __builtin_amdgcn_sched_barrier(0);
        __builtin_amdgcn_s_barrier();
        __builtin_amdgcn_sched_barrier(0);
        cur ^= 1;
    }

    if (sec < 2) {
#pragma unroll
        for (int mi = 0; mi < 4; mi++)
#pragma unroll
            for (int ni = 0; ni < 4; ni++)
#pragma unroll
                for (int r2 = 0; r2 < 4; r2++) {
                    int m = bm0 + wm + mi * 16 + lh * 4 + r2;
                    int nc = bn0 + wn + ni * 16 + lr;
                    vv[(size_t)m * 512 + nc] = f2bf(acc[mi][ni][r2]);
                }
    } else {
#pragma unroll
        for (int ni = 0; ni < 4; ni++) {
            const int c = wn + ni * 16 + lr;
            if (c < 40) {
                const int h = c / 5, q = c - h * 5;
                float* prow = &pglob[((size_t)(b * 8 + h) * 5 + q) * 1280];
#pragma unroll
                for (int mi = 0; mi < 4; mi++)
#pragma unroll
                    for (int r2 = 0; r2 < 4; r2++) {
                        int m = bm0 + wm + mi * 16 + lh * 4 + r2;
                        int j = m & 255;
                        prow[j * 5 + t5] = acc[mi][ni][r2];
                    }
            } else if (c < 80) {
#pragma unroll
                for (int mi = 0; mi < 4; mi++)
#pragma unroll
                    for (int r2 = 0; r2 < 4; r2++) {
                        int m = bm0 + wm + mi * 16 + lh * 4 + r2;
                        vascore[(size_t)m * 40 + (c - 40)] = acc[mi][ni][r2];
                    }
            }
        }
    }
}

// ---------------- wbuild_all: w-tilde score vectors + vo vectors, one launch ----------------
// blk <128: wcomb compute (rows 0..79 only); >=128: vob (bh=blk-128).
__global__ __launch_bounds__(512) void wbuild_all(const float* __restrict__ Wv,
                                                  const float* __restrict__ Wo,
                                                  const u16* __restrict__ aqkv,
                                                  u16* __restrict__ wcomb,
                                                  u16* __restrict__ vob) {
    const int blk = blockIdx.x;
    const int t = threadIdx.x;
    if (blk < 128) {
        __shared__ float avec[20][64];
        const int kind = blk & 1, h = (blk >> 1) & 7, vc = blk >> 4;
        const int v0 = vc * 20;
        const int aoff = (kind == 0) ? 0 : 512;
        for (int i = t; i < 1280; i += 512) {
            int vi = i >> 6, d = i & 63;
            int v = v0 + vi, b = v / 5, q = v - b * 5;
            avec[vi][d] = bf2f(aqkv[(size_t)(b * 5 + q) * 1536 + aoff + h * 64 + d]);
        }
        const int k = t;
        const int colbase = (kind == 0) ? (512 + h * 64) : (h * 64);
        float wr[64];
#pragma unroll
        for (int d = 0; d < 64; d += 4) {
            float4 w4 = *(const float4*)&Wv[(size_t)k * 1536 + colbase + d];
            wr[d] = w4.x; wr[d + 1] = w4.y; wr[d + 2] = w4.z; wr[d + 3] = w4.w;
        }
        __syncthreads();
        for (int vi = 0; vi < 20; vi++) {
            float acc = 0.f;
#pragma unroll
            for (int d = 0; d < 64; d++) acc += wr[d] * avec[vi][d];
            int v = v0 + vi, b = v / 5, q = v - b * 5;
            int c = kind * 40 + h * 5 + q;
            wcomb[((size_t)b * 256 + c) * 512 + k] = f2bf(acc);
        }
        return;
    }
    // vob: bh = blk-128 in [0,256)
    {
        __shared__ float vaL[5][64];
        const int bh = blk - 128;
        const int b = bh >> 3, h = bh & 7;
        for (int i = t; i < 320; i += 512) {
            int q = i >> 6, d = i & 63;
            vaL[q][d] = bf2f(aqkv[(size_t)(b * 5 + q) * 1536 + 1024 + h * 64 + d]);
        }
        __syncthreads();
        const int c = t;                        // 0..511
        float a0 = 0, a1 = 0, a2 = 0, a3 = 0, a4 = 0;
#pragma unroll 8
        for (int d = 0; d < 64; d++) {
            float w = Wo[(size_t)(h * 64 + d) * 512 + c];
            a0 += w * vaL[0][d];
            a1 += w * vaL[1][d];
            a2 += w * vaL[2][d];
            a3 += w * vaL[3][d];
            a4 += w * vaL[4][d];
        }
        const size_t base = ((size_t)b * 512 + c) * 64;
        vob[base + h * 5]     = f2bf(a0);
        vob[base + h * 5 + 1] = f2bf(a1);
        vob[base + h * 5 + 2] = f2bf(a2);
        vob[base + h * 5 + 3] = f2bf(a3);
        vob[base + h * 5 + 4] = f2bf(a4);
        if (h == 0) {
#pragma unroll
            for (int i = 40; i < 64; i++) vob[base + i] = 0;
        }
    }
}

// ---------------- vaout: fused va-softmax + (p @ vob) mini-GEMM -> out V rows ----------
// grid 1280 = bt(160) x mh(2) x nh(4); 256 thr = 4 waves. K=64 (40 used).
__global__ __launch_bounds__(256) void vaout(const float* __restrict__ vascore,
                                             const float* __restrict__ mask,
                                             const u16* __restrict__ vob,
                                             const float* __restrict__ bo,
                                             float* __restrict__ out) {
    __shared__ u16 As[128][64];
    __shared__ u16 Bs[128][64];
    const int blk = blockIdx.x;
    const int nh = blk & 3, mh = (blk >> 2) & 1, bt = blk >> 3;
    const int b = bt / 5;
    const int t = threadIdx.x;
    if (t < 128) {
        const int rr = mh * 128 + t;
        const size_t m = (size_t)bt * 256 + rr;
        const float mval = mask[m] * 0.125f;
        const float* sp = &vascore[m * 40];
        u16 prow[64];
#pragma unroll
        for (int h = 0; h < 8; h++) {
            float r0 = sp[h * 5] * mval, r1 = sp[h * 5 + 1] * mval, r2 = sp[h * 5 + 2] * mval;
            float r3 = sp[h * 5 + 3] * mval, r4 = sp[h * 5 + 4] * mval;
            float mx = fmaxf(fmaxf(fmaxf(r0, r1), fmaxf(r2, r3)), r4);
            float e0 = __expf(r0 - mx), e1 = __expf(r1 - mx), e2 = __expf(r2 - mx);
            float e3 = __expf(r3 - mx), e4 = __expf(r4 - mx);
            float inv = 1.f / (e0 + e1 + e2 + e3 + e4);
            prow[h * 5]     = f2bf(e0 * inv);
            prow[h * 5 + 1] = f2bf(e1 * inv);
            prow[h * 5 + 2] = f2bf(e2 * inv);
            prow[h * 5 + 3] = f2bf(e3 * inv);
            prow[h * 5 + 4] = f2bf(e4 * inv);
        }
#pragma unroll
        for (int i = 40; i < 64; i++) prow[i] = 0;
#pragma unroll
        for (int s = 0; s < 8; s++)
            *(u16x8*)&As[t][s * 8] = *(u16x8*)&prow[s * 8];
    }
    for (int i = t; i < 1024; i += 256) {
        int r = i >> 3, seg = i & 7;
        *(u16x8*)&Bs[r][seg * 8] =
            *(const u16x8*)&vob[((size_t)b * 512 + nh * 128 + r) * 64 + seg * 8];
    }
    __syncthreads();

    const int wave = t >> 6, lane = t & 63;
    const int wm = (wave >> 1) * 64, wn = (wave & 1) * 64;
    const int lr = lane & 15, lh = lane >> 4;
    f32x4 acc[4][4] = {};
#pragma unroll
    for (int kk = 0; kk < 2; kk++) {
        bf16x8 af[4], bfr[4];
#pragma unroll
        for (int mi = 0; mi < 4; mi++)
            af[mi] = *(const bf16x8*)&As[wm + mi * 16 + lr][kk * 32 + lh * 8];
#pragma unroll
        for (int ni = 0; ni < 4; ni++)
            bfr[ni] = *(const bf16x8*)&Bs[wn + ni * 16 + lr][kk * 32 + lh * 8];
#pragma unroll
        for (int mi = 0; mi < 4; mi++)
#pragma unroll
            for (int ni = 0; ni < 4; ni++)
                acc[mi][ni] = __builtin_amdgcn_mfma_f32_16x16x32_bf16(
                    af[mi], bfr[ni], acc[mi][ni], 0, 0, 0);
    }

    const size_t obase = ((size_t)bt * 257 + 1 + mh * 128) * 512 + nh * 128;
#pragma unroll
    for (int mi = 0; mi < 4; mi++)
#pragma unroll
        for (int ni = 0; ni < 4; ni++)
#pragma unroll
            for (int r2 = 0; r2 < 4; r2++) {
                int row = wm + mi * 16 + lh * 4 + r2;
                int col = wn + ni * 16 + lr;
                out[obase + (size_t)row * 512 + col] = acc[mi][ni][r2] + bo[nh * 128 + col];
            }
}

// ---------------- av_finish: softmax (LDS) + PV + reduce -> catA compact ----------------
// grid 256 = (bi,hd); 1024 threads = 16 waves.
__global__ __launch_bounds__(1024) void av_finish(const u16* __restrict__ vv,
                                                  const float* __restrict__ pglob,
                                                  u16* __restrict__ catA) {
    __shared__ float pl[5][1280];
    __shared__ float pbuf[16][5][64];
    const int bh = blockIdx.x;
    const int bi = bh >> 3, hd = bh & 7;
    const int t = threadIdx.x;
    for (int i = t; i < 6400; i += 1024) {
        pl[0][i] = pglob[(size_t)bh * 6400 + i] * 0.125f;
    }
    __syncthreads();
    const int wave = t >> 6, lane = t & 63;
    if (wave < 5) {
        float v[20];
        float mx = -3.4e38f;
#pragma unroll
        for (int i = 0; i < 20; i++) {
            v[i] = pl[wave][lane + i * 64];
            mx = fmaxf(mx, v[i]);
        }
#pragma unroll
        for (int off = 32; off > 0; off >>= 1) mx = fmaxf(mx, __shfl_xor(mx, off));
        float sum = 0.f;
#pragma unroll
        for (int i = 0; i < 20; i++) {
            v[i] = __expf(v[i] - mx);
            sum += v[i];
        }
#pragma unroll
        for (int off = 32; off > 0; off >>= 1) sum += __shfl_xor(sum, off);
        const float inv = 1.f / sum;
#pragma unroll
        for (int i = 0; i < 20; i++) pl[wave][lane + i * 64] = v[i] * inv;
    }
    __syncthreads();
    {
        float a0 = 0, a1 = 0, a2 = 0, a3 = 0, a4 = 0;
        const int j0 = wave * 16;
        for (int jj = 0; jj < 16; jj++) {
            const int j = j0 + jj;
#pragma unroll
            for (int t5 = 0; t5 < 5; t5++) {
                float v = bf2f(vv[(size_t)((bi * 5 + t5) * 256 + j) * 512 + hd * 64 + lane]);
                const int s = j * 5 + t5;
                a0 += pl[0][s] * v;
                a1 += pl[1][s] * v;
                a2 += pl[2][s] * v;
                a3 += pl[3][s] * v;
                a4 += pl[4][s] * v;
            }
        }
        pbuf[wave][0][lane] = a0;
        pbuf[wave][1][lane] = a1;
        pbuf[wave][2][lane] = a2;
        pbuf[wave][3][lane] = a3;
        pbuf[wave][4][lane] = a4;
    }
    __syncthreads();
    if (t < 320) {
        const int q = t >> 6, d = t & 63;
        float s = 0.f;
#pragma unroll
        for (int w = 0; w < 16; w++) s += pbuf[w][q][d];
        catA[(size_t)(bi * 5 + q) * 512 + hd * 64 + d] = f2bf(s);
    }
}

extern "C" void kernel_launch(void* const* d_in, const int* in_sizes, int n_in,
                              void* d_out, int out_size, void* d_ws, size_t ws_size,
                              hipStream_t stream) {
    const float* x    = (const float*)d_in[0];  // (160,257,512) f32
    const float* mask = (const float*)d_in[1];  // (160,256) f32
    const float* Wv   = (const float*)d_in[2];  // (512,1536) f32
    const float* Wa   = (const float*)d_in[3];  // (512,1536) f32
    const float* Wo   = (const float*)d_in[4];  // (512,512) f32
    const float* bo   = (const float*)d_in[5];  // (512,) f32
    float* out = (float*)d_out;

    char* ws = (char*)d_ws;
    u16*   xb      = (u16*)(ws);                  // 42,106,880
    u16*   WvTv    = (u16*)(ws + 42106880);       //    524,288
    u16*   WaT     = (u16*)(ws + 42631168);       //  1,572,864
    u16*   WoT     = (u16*)(ws + 44204032);       //    524,288
    u16*   aqkv    = (u16*)(ws + 44728320);       //    491,520
    u16*   wcomb   = (u16*)(ws + 45219840);       //  8,388,608  [32][256][512] bf16
    u16*   vv      = (u16*)(ws + 53608448);       // 41,943,040  [40960][512] bf16
    float* vascore = (float*)(ws + 95551488);     //  6,553,600  [40960][40] f32
    float* pglob   = (float*)(ws + 102105088);    //  6,553,600  [1280][1280] f32
    u16*   catA    = (u16*)(ws + 108658688);      //  1,310,720  [160][512] bf16 (padded)
    u16*   vob     = (u16*)(ws + 109969408);      //  2,097,152  [32][512][64] bf16 -> ~112 MB

    prep<<<dim3(10600), 256, 0, stream>>>(x, Wv, Wa, Wo, xb, WvTv, WaT, WoT);

    // a_qkv = A @ Wa_qkv (MFMA path — fast for K=512)
    gemm_k<2, 0><<<dim3(12, 2), 256, 0, stream>>>(xb, WaT, aqkv, nullptr, 160, 1536, 512);

    // combined vectors for scores and fused out-proj (one launch)
    wbuild_all<<<dim3(384), 512, 0, stream>>>(Wv, Wo, aqkv, wcomb, vob);

    // fused: vv = V @ Wv_v  AND  raw scores (av -> pglob, va -> vascore)
    gemm_vs<<<dim3(480), 1024, 0, stream>>>(xb, WvTv, wcomb, vv, pglob, vascore);

    // va path fused with out-proj: softmax5 + p @ vob -> out V rows (+bias)
    vaout<<<dim3(1280), 256, 0, stream>>>(vascore, mask, vob, bo, out);

    // av: softmax + PV + reduce -> catA compact
    av_finish<<<dim3(256), 1024, 0, stream>>>(vv, pglob, catA);

    // out A rows = catA @ Wo + bo  (M=160, out row map r*257)
    gemm_k<0, 2><<<dim3(4, 2), 256, 0, stream>>>(catA, WoT, out, bo, 160, 512, 512);
}

// Round 25
// 157.166 us; speedup vs baseline: 1.0043x; 1.0043x over previous
//
#include <hip/hip_runtime.h>
#include <hip/hip_bf16.h>

typedef unsigned short u16;
typedef __bf16 bf16x8 __attribute__((ext_vector_type(8)));
typedef u16 u16x8 __attribute__((ext_vector_type(8)));
typedef float f32x4 __attribute__((ext_vector_type(4)));

__device__ __forceinline__ float bf2f(u16 u) {
    return __uint_as_float(((unsigned)u) << 16);
}
__device__ __forceinline__ u16 f2bf(float f) {
    unsigned u = __float_as_uint(f);
    unsigned r = (u + 0x7fffu + ((u >> 16) & 1u)) >> 16;
    return (u16)r;
}

// async global->LDS, 16B per lane. dst is wave-uniform base; HW adds lane*16.
__device__ __forceinline__ void gl_lds16(const u16* g, u16* l) {
    __builtin_amdgcn_global_load_lds(
        (const __attribute__((address_space(1))) void*)g,
        (__attribute__((address_space(3))) void*)l, 16, 0, 0);
}

// ---------------- fused prep: x f32->bf16 convert + 3 weight transposes ----------------
__global__ __launch_bounds__(256) void prep(const float* __restrict__ x,
                                            const float* __restrict__ Wv,
                                            const float* __restrict__ Wa,
                                            const float* __restrict__ Wo,
                                            u16* __restrict__ xb,
                                            u16* __restrict__ WvTv,
                                            u16* __restrict__ WaT,
                                            u16* __restrict__ WoT) {
    __shared__ float tile[64][65];
    int blk = blockIdx.x;
    if (blk < 10280) {
        int i = (blk * 256 + threadIdx.x) * 8;
        float4 a = *(const float4*)&x[i];
        float4 b = *(const float4*)&x[i + 4];
        u16x8 o;
        o[0] = f2bf(a.x); o[1] = f2bf(a.y); o[2] = f2bf(a.z); o[3] = f2bf(a.w);
        o[4] = f2bf(b.x); o[5] = f2bf(b.y); o[6] = f2bf(b.z); o[7] = f2bf(b.w);
        *(u16x8*)&xb[i] = o;
        return;
    }
    blk -= 10280;
    const float* W; u16* WT; int N, stride, coff;
    if (blk < 64)       { W = Wv; WT = WvTv; N = 512;  stride = 1536; coff = 1024; }
    else if (blk < 256) { W = Wa; WT = WaT;  N = 1536; stride = 1536; coff = 0; blk -= 64; }
    else                { W = Wo; WT = WoT;  N = 512;  stride = 512;  coff = 0; blk -= 256; }
    const int nt = N >> 6;
    const int k0 = (blk / nt) << 6;
    const int n0 = (blk % nt) << 6;
    for (int i = threadIdx.x; i < 4096; i += 256) {
        int r = i >> 6, c = i & 63;
        tile[r][c] = W[(size_t)(k0 + r) * stride + coff + n0 + c];
    }
    __syncthreads();
    for (int i = threadIdx.x; i < 4096; i += 256) {
        int r = i >> 6, c = i & 63;
        WT[(size_t)(n0 + r) * 512 + k0 + c] = f2bf(tile[c][r]);
    }
}

// ---------------- small m97-style GEMM ----------
// MODE 0: row r->r (clamp). MODE 2: row r->r*257 (clamp).
// OUTF 0: bf16 out. OUTF 2: f32 out + bias, out row map r*257.
template <int MODE, int OUTF>
__global__ __launch_bounds__(256) void gemm_k(const u16* __restrict__ A,
                                              const u16* __restrict__ Bt,
                                              void* __restrict__ Cv,
                                              const float* __restrict__ bias,
                                              int M, int N, int K) {
    __shared__ u16 As[128][64];
    __shared__ u16 Bs[128][64];
    const int t = threadIdx.x;
    const int bn0 = blockIdx.x * 128;
    const int bm0 = blockIdx.y * 128;
    const int wave = t >> 6, lane = t & 63;
    const int wm = (wave >> 1) * 64, wn = (wave & 1) * 64;
    const int lr = lane & 15, lh = lane >> 4;
    const int srow = wave * 8 + (lane >> 3);
    const int scol = (lane & 7) * 8;

    f32x4 acc[4][4] = {};

    for (int kt = 0; kt < K; kt += 64) {
        __syncthreads();
#pragma unroll
        for (int i = 0; i < 4; i++) {
            int row = i * 32 + srow;
            int r = bm0 + row;
            long g;
            if (MODE == 0) g = (r < M) ? (long)r : 0l;
            else           g = (r < M) ? (long)r * 257 : 0l;
            gl_lds16(&A[g * K + kt + scol], &As[0][0] + i * 2048 + wave * 512);
            long nr = bn0 + row;
            gl_lds16(&Bt[nr * K + kt + scol], &Bs[0][0] + i * 2048 + wave * 512);
        }
        __syncthreads();
#pragma unroll
        for (int kk = 0; kk < 2; kk++) {
            bf16x8 af[4], bfr[4];
#pragma unroll
            for (int mi = 0; mi < 4; mi++)
                af[mi] = *(const bf16x8*)&As[wm + mi * 16 + lr][kk * 32 + lh * 8];
#pragma unroll
            for (int ni = 0; ni < 4; ni++)
                bfr[ni] = *(const bf16x8*)&Bs[wn + ni * 16 + lr][kk * 32 + lh * 8];
#pragma unroll
            for (int mi = 0; mi < 4; mi++)
#pragma unroll
                for (int ni = 0; ni < 4; ni++)
                    acc[mi][ni] = __builtin_amdgcn_mfma_f32_16x16x32_bf16(
                        af[mi], bfr[ni], acc[mi][ni], 0, 0, 0);
        }
    }

#pragma unroll
    for (int mi = 0; mi < 4; mi++)
#pragma unroll
        for (int ni = 0; ni < 4; ni++)
#pragma unroll
            for (int r2 = 0; r2 < 4; r2++) {
                int m = bm0 + wm + mi * 16 + lh * 4 + r2;
                if (m < M) {
                    int nc = bn0 + wn + ni * 16 + lr;
                    float v = acc[mi][ni][r2];
                    if (OUTF == 2) ((float*)Cv)[(size_t)m * 257 * N + nc] = v + bias[nc];
                    else           ((u16*)Cv)[(size_t)m * N + nc] = f2bf(v);
                }
            }
}

// ---------------- gemm_vs: fused vv-projection + scores, pipelined 256-tile ----------------
// Grid 480 (1-D, XCD-swizzled): wgid -> my = wgid/3 (= bt, 256 A-rows), sec = wgid%3.
// sec 0,1: vv tile, B = WvTv, cols sec*256..+256  -> vv bf16.
// sec 2:   scores, B = wcomb[b] (rows 0..79 real; rest feed only discarded cols).
// Round-25 change: "minimum 2-phase" K-loop (T3+T4 recipe, m230/m248v2 anchor):
// stage(next) issued BEFORE fragment reads; ONE vmcnt(0)+s_barrier per K-tile
// (was: MFMA -> bar -> stage -> vmcnt(4) -> bar). Ordering: readers of buf[cur^1]
// finished their lgkmcnt-fenced ds_reads before the previous barrier; per-wave
// vmcnt(0) + barrier publishes this tile's gl_lds writes before next tile's reads.
__global__ __launch_bounds__(1024) void gemm_vs(const u16* __restrict__ A,
                                                const u16* __restrict__ WvTv,
                                                const u16* __restrict__ wcomb,
                                                u16* __restrict__ vv,
                                                float* __restrict__ pglob,
                                                float* __restrict__ vascore) {
    __shared__ u16 As[2][256][64];
    __shared__ u16 Bs[2][256][64];
    const int t = threadIdx.x;
    const int nwg = gridDim.x;                 // 480, %8==0
    const int orig = blockIdx.x;
    const int qc = nwg >> 3;
    const int xcd = orig & 7, slot = orig >> 3;
    const int wgid = xcd * qc + slot;
    const int my = wgid / 3, sec = wgid % 3;   // my = bt
    const int bm0 = my * 256;
    const int bt = my, b = bt / 5, t5 = bt - b * 5;
    const int bn0 = (sec < 2) ? sec * 256 : 0;
    const u16* Bt = (sec < 2) ? WvTv : (wcomb + (size_t)b * 256 * 512);
    const int wave = t >> 6, lane = t & 63;
    const int wm = (wave >> 2) * 64, wn = (wave & 3) * 64;
    const int lr = lane & 15, lh = lane >> 4;
    const int xr = (lr & 7) << 3;              // read-side swizzle (row&7 == lr&7)
    u16* AsF = &As[0][0][0];
    u16* BsF = &Bs[0][0][0];

    const int gsa = ((lane & 7) ^ (lane >> 3)) * 8;
    auto stage = [&](int buf, int kt_) {
        const int kc = kt_ * 64;
#pragma unroll
        for (int j = 0; j < 2; j++) {
            int c0 = j * 1024 + wave * 64;
            int row = (c0 + lane) >> 3;
            int r = bm0 + row;
            long ga = (long)(r >> 8) * 257 + (r & 255) + 1;   // V rows of x
            gl_lds16(&A[ga * 512 + kc + gsa], AsF + buf * 16384 + c0 * 8);
            gl_lds16(&Bt[(long)(bn0 + row) * 512 + kc + gsa], BsF + buf * 16384 + c0 * 8);
        }
    };

    f32x4 acc[4][4] = {};

    stage(0, 0);
    __builtin_amdgcn_sched_barrier(0);
    asm volatile("s_waitcnt vmcnt(0)" ::: "memory");
    __builtin_amdgcn_s_barrier();
    __builtin_amdgcn_sched_barrier(0);

    int cur = 0;
    for (int kt = 0; kt < 8; kt++) {
        if (kt + 1 < 8) {
            stage(cur ^ 1, kt + 1);            // issue next tile's loads EARLY
            __builtin_amdgcn_sched_barrier(0);
        }
        __builtin_amdgcn_s_setprio(1);
#pragma unroll
        for (int kk = 0; kk < 2; kk++) {
            bf16x8 af[4], bfr[4];
#pragma unroll
            for (int mi = 0; mi < 4; mi++)
                af[mi] = *(const bf16x8*)&As[cur][wm + mi * 16 + lr][(kk * 32 + lh * 8) ^ xr];
#pragma unroll
            for (int ni = 0; ni < 4; ni++)
                bfr[ni] = *(const bf16x8*)&Bs[cur][wn + ni * 16 + lr][(kk * 32 + lh * 8) ^ xr];
#pragma unroll
            for (int mi = 0; mi < 4; mi++)
#pragma unroll
                for (int ni = 0; ni < 4; ni++)
                    acc[mi][ni] = __builtin_amdgcn_mfma_f32_16x16x32_bf16(
                        af[mi], bfr[ni], acc[mi][ni], 0, 0, 0);
        }
        __builtin_amdgcn_s_setprio(0);
        if (kt == 7) break;                    // epilogue has no LDS dependency
        __builtin_amdgcn_sched_barrier(0);
        asm volatile("s_waitcnt vmcnt(0)" ::: "memory");   // own stage loads landed
        __builtin_amdgcn_s_barrier();          // all reads of cur + writes of cur^1 done
        __builtin_amdgcn_sched_barrier(0);
        cur ^= 1;
    }

    if (sec < 2) {
#pragma unroll
        for (int mi = 0; mi < 4; mi++)
#pragma unroll
            for (int ni = 0; ni < 4; ni++)
#pragma unroll
                for (int r2 = 0; r2 < 4; r2++) {
                    int m = bm0 + wm + mi * 16 + lh * 4 + r2;
                    int nc = bn0 + wn + ni * 16 + lr;
                    vv[(size_t)m * 512 + nc] = f2bf(acc[mi][ni][r2]);
                }
    } else {
#pragma unroll
        for (int ni = 0; ni < 4; ni++) {
            const int c = wn + ni * 16 + lr;
            if (c < 40) {
                const int h = c / 5, q = c - h * 5;
                float* prow = &pglob[((size_t)(b * 8 + h) * 5 + q) * 1280];
#pragma unroll
                for (int mi = 0; mi < 4; mi++)
#pragma unroll
                    for (int r2 = 0; r2 < 4; r2++) {
                        int m = bm0 + wm + mi * 16 + lh * 4 + r2;
                        int j = m & 255;
                        prow[j * 5 + t5] = acc[mi][ni][r2];
                    }
            } else if (c < 80) {
#pragma unroll
                for (int mi = 0; mi < 4; mi++)
#pragma unroll
                    for (int r2 = 0; r2 < 4; r2++) {
                        int m = bm0 + wm + mi * 16 + lh * 4 + r2;
                        vascore[(size_t)m * 40 + (c - 40)] = acc[mi][ni][r2];
                    }
            }
        }
    }
}

// ---------------- wbuild_all: w-tilde score vectors + vo vectors, one launch ----------------
// blk <128: wcomb compute (rows 0..79 only); >=128: vob (bh=blk-128).
__global__ __launch_bounds__(512) void wbuild_all(const float* __restrict__ Wv,
                                                  const float* __restrict__ Wo,
                                                  const u16* __restrict__ aqkv,
                                                  u16* __restrict__ wcomb,
                                                  u16* __restrict__ vob) {
    const int blk = blockIdx.x;
    const int t = threadIdx.x;
    if (blk < 128) {
        __shared__ float avec[20][64];
        const int kind = blk & 1, h = (blk >> 1) & 7, vc = blk >> 4;
        const int v0 = vc * 20;
        const int aoff = (kind == 0) ? 0 : 512;
        for (int i = t; i < 1280; i += 512) {
            int vi = i >> 6, d = i & 63;
            int v = v0 + vi, b = v / 5, q = v - b * 5;
            avec[vi][d] = bf2f(aqkv[(size_t)(b * 5 + q) * 1536 + aoff + h * 64 + d]);
        }
        const int k = t;
        const int colbase = (kind == 0) ? (512 + h * 64) : (h * 64);
        float wr[64];
#pragma unroll
        for (int d = 0; d < 64; d += 4) {
            float4 w4 = *(const float4*)&Wv[(size_t)k * 1536 + colbase + d];
            wr[d] = w4.x; wr[d + 1] = w4.y; wr[d + 2] = w4.z; wr[d + 3] = w4.w;
        }
        __syncthreads();
        for (int vi = 0; vi < 20; vi++) {
            float acc = 0.f;
#pragma unroll
            for (int d = 0; d < 64; d++) acc += wr[d] * avec[vi][d];
            int v = v0 + vi, b = v / 5, q = v - b * 5;
            int c = kind * 40 + h * 5 + q;
            wcomb[((size_t)b * 256 + c) * 512 + k] = f2bf(acc);
        }
        return;
    }
    // vob: bh = blk-128 in [0,256)
    {
        __shared__ float vaL[5][64];
        const int bh = blk - 128;
        const int b = bh >> 3, h = bh & 7;
        for (int i = t; i < 320; i += 512) {
            int q = i >> 6, d = i & 63;
            vaL[q][d] = bf2f(aqkv[(size_t)(b * 5 + q) * 1536 + 1024 + h * 64 + d]);
        }
        __syncthreads();
        const int c = t;                        // 0..511
        float a0 = 0, a1 = 0, a2 = 0, a3 = 0, a4 = 0;
#pragma unroll 8
        for (int d = 0; d < 64; d++) {
            float w = Wo[(size_t)(h * 64 + d) * 512 + c];
            a0 += w * vaL[0][d];
            a1 += w * vaL[1][d];
            a2 += w * vaL[2][d];
            a3 += w * vaL[3][d];
            a4 += w * vaL[4][d];
        }
        const size_t base = ((size_t)b * 512 + c) * 64;
        vob[base + h * 5]     = f2bf(a0);
        vob[base + h * 5 + 1] = f2bf(a1);
        vob[base + h * 5 + 2] = f2bf(a2);
        vob[base + h * 5 + 3] = f2bf(a3);
        vob[base + h * 5 + 4] = f2bf(a4);
        if (h == 0) {
#pragma unroll
            for (int i = 40; i < 64; i++) vob[base + i] = 0;
        }
    }
}

// ---------------- vaout: fused va-softmax + (p @ vob) mini-GEMM -> out V rows ----------
// grid 1280 = bt(160) x mh(2) x nh(4); 256 thr = 4 waves. K=64 (40 used).
__global__ __launch_bounds__(256) void vaout(const float* __restrict__ vascore,
                                             const float* __restrict__ mask,
                                             const u16* __restrict__ vob,
                                             const float* __restrict__ bo,
                                             float* __restrict__ out) {
    __shared__ u16 As[128][64];
    __shared__ u16 Bs[128][64];
    const int blk = blockIdx.x;
    const int nh = blk & 3, mh = (blk >> 2) & 1, bt = blk >> 3;
    const int b = bt / 5;
    const int t = threadIdx.x;
    if (t < 128) {
        const int rr = mh * 128 + t;
        const size_t m = (size_t)bt * 256 + rr;
        const float mval = mask[m] * 0.125f;
        const float* sp = &vascore[m * 40];
        u16 prow[64];
#pragma unroll
        for (int h = 0; h < 8; h++) {
            float r0 = sp[h * 5] * mval, r1 = sp[h * 5 + 1] * mval, r2 = sp[h * 5 + 2] * mval;
            float r3 = sp[h * 5 + 3] * mval, r4 = sp[h * 5 + 4] * mval;
            float mx = fmaxf(fmaxf(fmaxf(r0, r1), fmaxf(r2, r3)), r4);
            float e0 = __expf(r0 - mx), e1 = __expf(r1 - mx), e2 = __expf(r2 - mx);
            float e3 = __expf(r3 - mx), e4 = __expf(r4 - mx);
            float inv = 1.f / (e0 + e1 + e2 + e3 + e4);
            prow[h * 5]     = f2bf(e0 * inv);
            prow[h * 5 + 1] = f2bf(e1 * inv);
            prow[h * 5 + 2] = f2bf(e2 * inv);
            prow[h * 5 + 3] = f2bf(e3 * inv);
            prow[h * 5 + 4] = f2bf(e4 * inv);
        }
#pragma unroll
        for (int i = 40; i < 64; i++) prow[i] = 0;
#pragma unroll
        for (int s = 0; s < 8; s++)
            *(u16x8*)&As[t][s * 8] = *(u16x8*)&prow[s * 8];
    }
    for (int i = t; i < 1024; i += 256) {
        int r = i >> 3, seg = i & 7;
        *(u16x8*)&Bs[r][seg * 8] =
            *(const u16x8*)&vob[((size_t)b * 512 + nh * 128 + r) * 64 + seg * 8];
    }
    __syncthreads();

    const int wave = t >> 6, lane = t & 63;
    const int wm = (wave >> 1) * 64, wn = (wave & 1) * 64;
    const int lr = lane & 15, lh = lane >> 4;
    f32x4 acc[4][4] = {};
#pragma unroll
    for (int kk = 0; kk < 2; kk++) {
        bf16x8 af[4], bfr[4];
#pragma unroll
        for (int mi = 0; mi < 4; mi++)
            af[mi] = *(const bf16x8*)&As[wm + mi * 16 + lr][kk * 32 + lh * 8];
#pragma unroll
        for (int ni = 0; ni < 4; ni++)
            bfr[ni] = *(const bf16x8*)&Bs[wn + ni * 16 + lr][kk * 32 + lh * 8];
#pragma unroll
        for (int mi = 0; mi < 4; mi++)
#pragma unroll
            for (int ni = 0; ni < 4; ni++)
                acc[mi][ni] = __builtin_amdgcn_mfma_f32_16x16x32_bf16(
                    af[mi], bfr[ni], acc[mi][ni], 0, 0, 0);
    }

    const size_t obase = ((size_t)bt * 257 + 1 + mh * 128) * 512 + nh * 128;
#pragma unroll
    for (int mi = 0; mi < 4; mi++)
#pragma unroll
        for (int ni = 0; ni < 4; ni++)
#pragma unroll
            for (int r2 = 0; r2 < 4; r2++) {
                int row = wm + mi * 16 + lh * 4 + r2;
                int col = wn + ni * 16 + lr;
                out[obase + (size_t)row * 512 + col] = acc[mi][ni][r2] + bo[nh * 128 + col];
            }
}

// ---------------- av_finish: softmax (LDS) + PV + reduce -> catA compact ----------------
// grid 256 = (bi,hd); 1024 threads = 16 waves.
__global__ __launch_bounds__(1024) void av_finish(const u16* __restrict__ vv,
                                                  const float* __restrict__ pglob,
                                                  u16* __restrict__ catA) {
    __shared__ float pl[5][1280];
    __shared__ float pbuf[16][5][64];
    const int bh = blockIdx.x;
    const int bi = bh >> 3, hd = bh & 7;
    const int t = threadIdx.x;
    for (int i = t; i < 6400; i += 1024) {
        pl[0][i] = pglob[(size_t)bh * 6400 + i] * 0.125f;
    }
    __syncthreads();
    const int wave = t >> 6, lane = t & 63;
    if (wave < 5) {
        float v[20];
        float mx = -3.4e38f;
#pragma unroll
        for (int i = 0; i < 20; i++) {
            v[i] = pl[wave][lane + i * 64];
            mx = fmaxf(mx, v[i]);
        }
#pragma unroll
        for (int off = 32; off > 0; off >>= 1) mx = fmaxf(mx, __shfl_xor(mx, off));
        float sum = 0.f;
#pragma unroll
        for (int i = 0; i < 20; i++) {
            v[i] = __expf(v[i] - mx);
            sum += v[i];
        }
#pragma unroll
        for (int off = 32; off > 0; off >>= 1) sum += __shfl_xor(sum, off);
        const float inv = 1.f / sum;
#pragma unroll
        for (int i = 0; i < 20; i++) pl[wave][lane + i * 64] = v[i] * inv;
    }
    __syncthreads();
    {
        float a0 = 0, a1 = 0, a2 = 0, a3 = 0, a4 = 0;
        const int j0 = wave * 16;
        for (int jj = 0; jj < 16; jj++) {
            const int j = j0 + jj;
#pragma unroll
            for (int t5 = 0; t5 < 5; t5++) {
                float v = bf2f(vv[(size_t)((bi * 5 + t5) * 256 + j) * 512 + hd * 64 + lane]);
                const int s = j * 5 + t5;
                a0 += pl[0][s] * v;
                a1 += pl[1][s] * v;
                a2 += pl[2][s] * v;
                a3 += pl[3][s] * v;
                a4 += pl[4][s] * v;
            }
        }
        pbuf[wave][0][lane] = a0;
        pbuf[wave][1][lane] = a1;
        pbuf[wave][2][lane] = a2;
        pbuf[wave][3][lane] = a3;
        pbuf[wave][4][lane] = a4;
    }
    __syncthreads();
    if (t < 320) {
        const int q = t >> 6, d = t & 63;
        float s = 0.f;
#pragma unroll
        for (int w = 0; w < 16; w++) s += pbuf[w][q][d];
        catA[(size_t)(bi * 5 + q) * 512 + hd * 64 + d] = f2bf(s);
    }
}

extern "C" void kernel_launch(void* const* d_in, const int* in_sizes, int n_in,
                              void* d_out, int out_size, void* d_ws, size_t ws_size,
                              hipStream_t stream) {
    const float* x    = (const float*)d_in[0];  // (160,257,512) f32
    const float* mask = (const float*)d_in[1];  // (160,256) f32
    const float* Wv   = (const float*)d_in[2];  // (512,1536) f32
    const float* Wa   = (const float*)d_in[3];  // (512,1536) f32
    const float* Wo   = (const float*)d_in[4];  // (512,512) f32
    const float* bo   = (const float*)d_in[5];  // (512,) f32
    float* out = (float*)d_out;

    char* ws = (char*)d_ws;
    u16*   xb      = (u16*)(ws);                  // 42,106,880
    u16*   WvTv    = (u16*)(ws + 42106880);       //    524,288
    u16*   WaT     = (u16*)(ws + 42631168);       //  1,572,864
    u16*   WoT     = (u16*)(ws + 44204032);       //    524,288
    u16*   aqkv    = (u16*)(ws + 44728320);       //    491,520
    u16*   wcomb   = (u16*)(ws + 45219840);       //  8,388,608  [32][256][512] bf16
    u16*   vv      = (u16*)(ws + 53608448);       // 41,943,040  [40960][512] bf16
    float* vascore = (float*)(ws + 95551488);     //  6,553,600  [40960][40] f32
    float* pglob   = (float*)(ws + 102105088);    //  6,553,600  [1280][1280] f32
    u16*   catA    = (u16*)(ws + 108658688);      //  1,310,720  [160][512] bf16 (padded)
    u16*   vob     = (u16*)(ws + 109969408);      //  2,097,152  [32][512][64] bf16 -> ~112 MB

    prep<<<dim3(10600), 256, 0, stream>>>(x, Wv, Wa, Wo, xb, WvTv, WaT, WoT);

    // a_qkv = A @ Wa_qkv (MFMA path — fast for K=512)
    gemm_k<2, 0><<<dim3(12, 2), 256, 0, stream>>>(xb, WaT, aqkv, nullptr, 160, 1536, 512);

    // combined vectors for scores and fused out-proj (one launch)
    wbuild_all<<<dim3(384), 512, 0, stream>>>(Wv, Wo, aqkv, wcomb, vob);

    // fused: vv = V @ Wv_v  AND  raw scores (av -> pglob, va -> vascore)
    gemm_vs<<<dim3(480), 1024, 0, stream>>>(xb, WvTv, wcomb, vv, pglob, vascore);

    // va path fused with out-proj: softmax5 + p @ vob -> out V rows (+bias)
    vaout<<<dim3(1280), 256, 0, stream>>>(vascore, mask, vob, bo, out);

    // av: softmax + PV + reduce -> catA compact
    av_finish<<<dim3(256), 1024, 0, stream>>>(vv, pglob, catA);

    // out A rows = catA @ Wo + bo  (M=160, out row map r*257)
    gemm_k<0, 2><<<dim3(4, 2), 256, 0, stream>>>(catA, WoT, out, bo, 160, 512, 512);
}

// Round 26
// 154.816 us; speedup vs baseline: 1.0196x; 1.0152x over previous
//
#include <hip/hip_runtime.h>
#include <hip/hip_bf16.h>

typedef unsigned short u16;
typedef __bf16 bf16x8 __attribute__((ext_vector_type(8)));
typedef u16 u16x8 __attribute__((ext_vector_type(8)));
typedef float f32x4 __attribute__((ext_vector_type(4)));

__device__ __forceinline__ float bf2f(u16 u) {
    return __uint_as_float(((unsigned)u) << 16);
}
__device__ __forceinline__ u16 f2bf(float f) {
    unsigned u = __float_as_uint(f);
    unsigned r = (u + 0x7fffu + ((u >> 16) & 1u)) >> 16;
    return (u16)r;
}

// async global->LDS, 16B per lane. dst is wave-uniform base; HW adds lane*16.
__device__ __forceinline__ void gl_lds16(const u16* g, u16* l) {
    __builtin_amdgcn_global_load_lds(
        (const __attribute__((address_space(1))) void*)g,
        (__attribute__((address_space(3))) void*)l, 16, 0, 0);
}

// ---------------- fused prep: x f32->bf16 convert + 3 weight transposes ----------------
__global__ __launch_bounds__(256) void prep(const float* __restrict__ x,
                                            const float* __restrict__ Wv,
                                            const float* __restrict__ Wa,
                                            const float* __restrict__ Wo,
                                            u16* __restrict__ xb,
                                            u16* __restrict__ WvTv,
                                            u16* __restrict__ WaT,
                                            u16* __restrict__ WoT) {
    __shared__ float tile[64][65];
    int blk = blockIdx.x;
    if (blk < 10280) {
        int i = (blk * 256 + threadIdx.x) * 8;
        float4 a = *(const float4*)&x[i];
        float4 b = *(const float4*)&x[i + 4];
        u16x8 o;
        o[0] = f2bf(a.x); o[1] = f2bf(a.y); o[2] = f2bf(a.z); o[3] = f2bf(a.w);
        o[4] = f2bf(b.x); o[5] = f2bf(b.y); o[6] = f2bf(b.z); o[7] = f2bf(b.w);
        *(u16x8*)&xb[i] = o;
        return;
    }
    blk -= 10280;
    const float* W; u16* WT; int N, stride, coff;
    if (blk < 64)       { W = Wv; WT = WvTv; N = 512;  stride = 1536; coff = 1024; }
    else if (blk < 256) { W = Wa; WT = WaT;  N = 1536; stride = 1536; coff = 0; blk -= 64; }
    else                { W = Wo; WT = WoT;  N = 512;  stride = 512;  coff = 0; blk -= 256; }
    const int nt = N >> 6;
    const int k0 = (blk / nt) << 6;
    const int n0 = (blk % nt) << 6;
    for (int i = threadIdx.x; i < 4096; i += 256) {
        int r = i >> 6, c = i & 63;
        tile[r][c] = W[(size_t)(k0 + r) * stride + coff + n0 + c];
    }
    __syncthreads();
    for (int i = threadIdx.x; i < 4096; i += 256) {
        int r = i >> 6, c = i & 63;
        WT[(size_t)(n0 + r) * 512 + k0 + c] = f2bf(tile[c][r]);
    }
}

// ---------------- small m97-style GEMM ----------
// MODE 0: row r->r (clamp). MODE 2: row r->r*257 (clamp).
// OUTF 0: bf16 out. OUTF 2: f32 out + bias, out row map r*257.
template <int MODE, int OUTF>
__global__ __launch_bounds__(256) void gemm_k(const u16* __restrict__ A,
                                              const u16* __restrict__ Bt,
                                              void* __restrict__ Cv,
                                              const float* __restrict__ bias,
                                              int M, int N, int K) {
    __shared__ u16 As[128][64];
    __shared__ u16 Bs[128][64];
    const int t = threadIdx.x;
    const int bn0 = blockIdx.x * 128;
    const int bm0 = blockIdx.y * 128;
    const int wave = t >> 6, lane = t & 63;
    const int wm = (wave >> 1) * 64, wn = (wave & 1) * 64;
    const int lr = lane & 15, lh = lane >> 4;
    const int srow = wave * 8 + (lane >> 3);
    const int scol = (lane & 7) * 8;

    f32x4 acc[4][4] = {};

    for (int kt = 0; kt < K; kt += 64) {
        __syncthreads();
#pragma unroll
        for (int i = 0; i < 4; i++) {
            int row = i * 32 + srow;
            int r = bm0 + row;
            long g;
            if (MODE == 0) g = (r < M) ? (long)r : 0l;
            else           g = (r < M) ? (long)r * 257 : 0l;
            gl_lds16(&A[g * K + kt + scol], &As[0][0] + i * 2048 + wave * 512);
            long nr = bn0 + row;
            gl_lds16(&Bt[nr * K + kt + scol], &Bs[0][0] + i * 2048 + wave * 512);
        }
        __syncthreads();
#pragma unroll
        for (int kk = 0; kk < 2; kk++) {
            bf16x8 af[4], bfr[4];
#pragma unroll
            for (int mi = 0; mi < 4; mi++)
                af[mi] = *(const bf16x8*)&As[wm + mi * 16 + lr][kk * 32 + lh * 8];
#pragma unroll
            for (int ni = 0; ni < 4; ni++)
                bfr[ni] = *(const bf16x8*)&Bs[wn + ni * 16 + lr][kk * 32 + lh * 8];
#pragma unroll
            for (int mi = 0; mi < 4; mi++)
#pragma unroll
                for (int ni = 0; ni < 4; ni++)
                    acc[mi][ni] = __builtin_amdgcn_mfma_f32_16x16x32_bf16(
                        af[mi], bfr[ni], acc[mi][ni], 0, 0, 0);
        }
    }

#pragma unroll
    for (int mi = 0; mi < 4; mi++)
#pragma unroll
        for (int ni = 0; ni < 4; ni++)
#pragma unroll
            for (int r2 = 0; r2 < 4; r2++) {
                int m = bm0 + wm + mi * 16 + lh * 4 + r2;
                if (m < M) {
                    int nc = bn0 + wn + ni * 16 + lr;
                    float v = acc[mi][ni][r2];
                    if (OUTF == 2) ((float*)Cv)[(size_t)m * 257 * N + nc] = v + bias[nc];
                    else           ((u16*)Cv)[(size_t)m * N + nc] = f2bf(v);
                }
            }
}

// ---------------- gemm_vs: fused vv-projection + scores, pipelined 256-tile ----------------
// Grid 480 (1-D, XCD-swizzled): wgid -> my = wgid/3 (= bt, 256 A-rows), sec = wgid%3.
// sec 0,1: vv tile, B = WvTv, cols sec*256..+256  -> vv bf16.
// sec 2:   scores, B = wcomb[b] (rows 0..79 real; rest feed only discarded cols).
// Minimum 2-phase K-loop (round 25, best measured): stage(next) before fragment
// reads; one vmcnt(0)+s_barrier per K-tile. 16x16x32 MFMA, both-sides XOR swizzle.
__global__ __launch_bounds__(1024) void gemm_vs(const u16* __restrict__ A,
                                                const u16* __restrict__ WvTv,
                                                const u16* __restrict__ wcomb,
                                                u16* __restrict__ vv,
                                                float* __restrict__ pglob,
                                                float* __restrict__ vascore) {
    __shared__ u16 As[2][256][64];
    __shared__ u16 Bs[2][256][64];
    const int t = threadIdx.x;
    const int nwg = gridDim.x;                 // 480, %8==0
    const int orig = blockIdx.x;
    const int qc = nwg >> 3;
    const int xcd = orig & 7, slot = orig >> 3;
    const int wgid = xcd * qc + slot;
    const int my = wgid / 3, sec = wgid % 3;   // my = bt
    const int bm0 = my * 256;
    const int bt = my, b = bt / 5, t5 = bt - b * 5;
    const int bn0 = (sec < 2) ? sec * 256 : 0;
    const u16* Bt = (sec < 2) ? WvTv : (wcomb + (size_t)b * 256 * 512);
    const int wave = t >> 6, lane = t & 63;
    const int wm = (wave >> 2) * 64, wn = (wave & 3) * 64;
    const int lr = lane & 15, lh = lane >> 4;
    const int xr = (lr & 7) << 3;              // read-side swizzle (row&7 == lr&7)
    u16* AsF = &As[0][0][0];
    u16* BsF = &Bs[0][0][0];

    const int gsa = ((lane & 7) ^ (lane >> 3)) * 8;
    auto stage = [&](int buf, int kt_) {
        const int kc = kt_ * 64;
#pragma unroll
        for (int j = 0; j < 2; j++) {
            int c0 = j * 1024 + wave * 64;
            int row = (c0 + lane) >> 3;
            int r = bm0 + row;
            long ga = (long)(r >> 8) * 257 + (r & 255) + 1;   // V rows of x
            gl_lds16(&A[ga * 512 + kc + gsa], AsF + buf * 16384 + c0 * 8);
            gl_lds16(&Bt[(long)(bn0 + row) * 512 + kc + gsa], BsF + buf * 16384 + c0 * 8);
        }
    };

    f32x4 acc[4][4] = {};

    stage(0, 0);
    __builtin_amdgcn_sched_barrier(0);
    asm volatile("s_waitcnt vmcnt(0)" ::: "memory");
    __builtin_amdgcn_s_barrier();
    __builtin_amdgcn_sched_barrier(0);

    int cur = 0;
    for (int kt = 0; kt < 8; kt++) {
        if (kt + 1 < 8) {
            stage(cur ^ 1, kt + 1);            // issue next tile's loads EARLY
            __builtin_amdgcn_sched_barrier(0);
        }
        __builtin_amdgcn_s_setprio(1);
#pragma unroll
        for (int kk = 0; kk < 2; kk++) {
            bf16x8 af[4], bfr[4];
#pragma unroll
            for (int mi = 0; mi < 4; mi++)
                af[mi] = *(const bf16x8*)&As[cur][wm + mi * 16 + lr][(kk * 32 + lh * 8) ^ xr];
#pragma unroll
            for (int ni = 0; ni < 4; ni++)
                bfr[ni] = *(const bf16x8*)&Bs[cur][wn + ni * 16 + lr][(kk * 32 + lh * 8) ^ xr];
#pragma unroll
            for (int mi = 0; mi < 4; mi++)
#pragma unroll
                for (int ni = 0; ni < 4; ni++)
                    acc[mi][ni] = __builtin_amdgcn_mfma_f32_16x16x32_bf16(
                        af[mi], bfr[ni], acc[mi][ni], 0, 0, 0);
        }
        __builtin_amdgcn_s_setprio(0);
        if (kt == 7) break;                    // epilogue has no LDS dependency
        __builtin_amdgcn_sched_barrier(0);
        asm volatile("s_waitcnt vmcnt(0)" ::: "memory");   // own stage loads landed
        __builtin_amdgcn_s_barrier();          // all reads of cur + writes of cur^1 done
        __builtin_amdgcn_sched_barrier(0);
        cur ^= 1;
    }

    if (sec < 2) {
#pragma unroll
        for (int mi = 0; mi < 4; mi++)
#pragma unroll
            for (int ni = 0; ni < 4; ni++)
#pragma unroll
                for (int r2 = 0; r2 < 4; r2++) {
                    int m = bm0 + wm + mi * 16 + lh * 4 + r2;
                    int nc = bn0 + wn + ni * 16 + lr;
                    vv[(size_t)m * 512 + nc] = f2bf(acc[mi][ni][r2]);
                }
    } else {
#pragma unroll
        for (int ni = 0; ni < 4; ni++) {
            const int c = wn + ni * 16 + lr;
            if (c < 40) {
                const int h = c / 5, q = c - h * 5;
                float* prow = &pglob[((size_t)(b * 8 + h) * 5 + q) * 1280];
#pragma unroll
                for (int mi = 0; mi < 4; mi++)
#pragma unroll
                    for (int r2 = 0; r2 < 4; r2++) {
                        int m = bm0 + wm + mi * 16 + lh * 4 + r2;
                        int j = m & 255;
                        prow[j * 5 + t5] = acc[mi][ni][r2];
                    }
            } else if (c < 80) {
#pragma unroll
                for (int mi = 0; mi < 4; mi++)
#pragma unroll
                    for (int r2 = 0; r2 < 4; r2++) {
                        int m = bm0 + wm + mi * 16 + lh * 4 + r2;
                        vascore[(size_t)m * 40 + (c - 40)] = acc[mi][ni][r2];
                    }
            }
        }
    }
}

// ---------------- wbuild_all: w-tilde score vectors + vo vectors, one launch ----------------
// blk <128: wcomb compute (rows 0..79 only); >=128: vob (bh=blk-128).
__global__ __launch_bounds__(512) void wbuild_all(const float* __restrict__ Wv,
                                                  const float* __restrict__ Wo,
                                                  const u16* __restrict__ aqkv,
                                                  u16* __restrict__ wcomb,
                                                  u16* __restrict__ vob) {
    const int blk = blockIdx.x;
    const int t = threadIdx.x;
    if (blk < 128) {
        __shared__ float avec[20][64];
        const int kind = blk & 1, h = (blk >> 1) & 7, vc = blk >> 4;
        const int v0 = vc * 20;
        const int aoff = (kind == 0) ? 0 : 512;
        for (int i = t; i < 1280; i += 512) {
            int vi = i >> 6, d = i & 63;
            int v = v0 + vi, b = v / 5, q = v - b * 5;
            avec[vi][d] = bf2f(aqkv[(size_t)(b * 5 + q) * 1536 + aoff + h * 64 + d]);
        }
        const int k = t;
        const int colbase = (kind == 0) ? (512 + h * 64) : (h * 64);
        float wr[64];
#pragma unroll
        for (int d = 0; d < 64; d += 4) {
            float4 w4 = *(const float4*)&Wv[(size_t)k * 1536 + colbase + d];
            wr[d] = w4.x; wr[d + 1] = w4.y; wr[d + 2] = w4.z; wr[d + 3] = w4.w;
        }
        __syncthreads();
        for (int vi = 0; vi < 20; vi++) {
            float acc = 0.f;
#pragma unroll
            for (int d = 0; d < 64; d++) acc += wr[d] * avec[vi][d];
            int v = v0 + vi, b = v / 5, q = v - b * 5;
            int c = kind * 40 + h * 5 + q;
            wcomb[((size_t)b * 256 + c) * 512 + k] = f2bf(acc);
        }
        return;
    }
    // vob: bh = blk-128 in [0,256)
    {
        __shared__ float vaL[5][64];
        const int bh = blk - 128;
        const int b = bh >> 3, h = bh & 7;
        for (int i = t; i < 320; i += 512) {
            int q = i >> 6, d = i & 63;
            vaL[q][d] = bf2f(aqkv[(size_t)(b * 5 + q) * 1536 + 1024 + h * 64 + d]);
        }
        __syncthreads();
        const int c = t;                        // 0..511
        float a0 = 0, a1 = 0, a2 = 0, a3 = 0, a4 = 0;
#pragma unroll 8
        for (int d = 0; d < 64; d++) {
            float w = Wo[(size_t)(h * 64 + d) * 512 + c];
            a0 += w * vaL[0][d];
            a1 += w * vaL[1][d];
            a2 += w * vaL[2][d];
            a3 += w * vaL[3][d];
            a4 += w * vaL[4][d];
        }
        const size_t base = ((size_t)b * 512 + c) * 64;
        vob[base + h * 5]     = f2bf(a0);
        vob[base + h * 5 + 1] = f2bf(a1);
        vob[base + h * 5 + 2] = f2bf(a2);
        vob[base + h * 5 + 3] = f2bf(a3);
        vob[base + h * 5 + 4] = f2bf(a4);
        if (h == 0) {
#pragma unroll
            for (int i = 40; i < 64; i++) vob[base + i] = 0;
        }
    }
}

// ---------------- attn_out: merged av_finish + vaout, 512 threads ----------------
// blk <256: av_finish (round-18 512-thr body verbatim): softmax(LDS) + PV -> catA.
// blk>=256: vaout 512-thr: blk2 = blk-256 = bt(160) x nh(4); As[256][64] covers
//           both mh halves, 8 waves -> 256x128 out tile (+bias).
__global__ __launch_bounds__(512) void attn_out(const u16* __restrict__ vv,
                                                const float* __restrict__ pglob,
                                                u16* __restrict__ catA,
                                                const float* __restrict__ vascore,
                                                const float* __restrict__ mask,
                                                const u16* __restrict__ vob,
                                                const float* __restrict__ bo,
                                                float* __restrict__ out) {
    __shared__ __align__(16) char shm[49152];
    const int blk = blockIdx.x;
    const int t = threadIdx.x;
    const int wave = t >> 6, lane = t & 63;

    if (blk < 256) {
        // ---- av_finish ----
        float* pl   = (float*)shm;              // [5][1280] = 25600 B
        float* pbuf = (float*)(shm + 25600);    // [8][5][64] = 10240 B
        const int bh = blk;
        const int bi = bh >> 3, hd = bh & 7;
        for (int i = t; i < 6400; i += 512)
            pl[i] = pglob[(size_t)bh * 6400 + i] * 0.125f;
        __syncthreads();
        if (wave < 5) {
            float v[20];
            float mx = -3.4e38f;
#pragma unroll
            for (int i = 0; i < 20; i++) {
                v[i] = pl[wave * 1280 + lane + i * 64];
                mx = fmaxf(mx, v[i]);
            }
#pragma unroll
            for (int off = 32; off > 0; off >>= 1) mx = fmaxf(mx, __shfl_xor(mx, off));
            float sum = 0.f;
#pragma unroll
            for (int i = 0; i < 20; i++) {
                v[i] = __expf(v[i] - mx);
                sum += v[i];
            }
#pragma unroll
            for (int off = 32; off > 0; off >>= 1) sum += __shfl_xor(sum, off);
            const float inv = 1.f / sum;
#pragma unroll
            for (int i = 0; i < 20; i++) pl[wave * 1280 + lane + i * 64] = v[i] * inv;
        }
        __syncthreads();
        {
            float a0 = 0, a1 = 0, a2 = 0, a3 = 0, a4 = 0;
            const int j0 = wave * 32;
            for (int jj = 0; jj < 32; jj++) {
                const int j = j0 + jj;
#pragma unroll
                for (int t5 = 0; t5 < 5; t5++) {
                    float v = bf2f(vv[(size_t)((bi * 5 + t5) * 256 + j) * 512 + hd * 64 + lane]);
                    const int s = j * 5 + t5;
                    a0 += pl[0 * 1280 + s] * v;
                    a1 += pl[1 * 1280 + s] * v;
                    a2 += pl[2 * 1280 + s] * v;
                    a3 += pl[3 * 1280 + s] * v;
                    a4 += pl[4 * 1280 + s] * v;
                }
            }
            pbuf[(wave * 5 + 0) * 64 + lane] = a0;
            pbuf[(wave * 5 + 1) * 64 + lane] = a1;
            pbuf[(wave * 5 + 2) * 64 + lane] = a2;
            pbuf[(wave * 5 + 3) * 64 + lane] = a3;
            pbuf[(wave * 5 + 4) * 64 + lane] = a4;
        }
        __syncthreads();
        if (t < 320) {
            const int q = t >> 6, d = t & 63;
            float s = 0.f;
#pragma unroll
            for (int w = 0; w < 8; w++) s += pbuf[(w * 5 + q) * 64 + d];
            catA[(size_t)(bi * 5 + q) * 512 + hd * 64 + d] = f2bf(s);
        }
        return;
    }

    // ---- vaout (512-thread) ----
    const int blk2 = blk - 256;               // 0..639
    const int nh = blk2 & 3, bt = blk2 >> 2;  // nh in [0,4), bt in [0,160)
    const int b = bt / 5;
    u16* As = (u16*)shm;                       // [256][64] = 32768 B
    u16* Bs = (u16*)(shm + 32768);             // [128][64] = 16384 B
    if (t < 256) {
        const int rr = t;                      // row in [0,256)
        const size_t m = (size_t)bt * 256 + rr;
        const float mval = mask[m] * 0.125f;
        const float* sp = &vascore[m * 40];
        u16 prow[64];
#pragma unroll
        for (int h = 0; h < 8; h++) {
            float r0 = sp[h * 5] * mval, r1 = sp[h * 5 + 1] * mval, r2 = sp[h * 5 + 2] * mval;
            float r3 = sp[h * 5 + 3] * mval, r4 = sp[h * 5 + 4] * mval;
            float mx = fmaxf(fmaxf(fmaxf(r0, r1), fmaxf(r2, r3)), r4);
            float e0 = __expf(r0 - mx), e1 = __expf(r1 - mx), e2 = __expf(r2 - mx);
            float e3 = __expf(r3 - mx), e4 = __expf(r4 - mx);
            float inv = 1.f / (e0 + e1 + e2 + e3 + e4);
            prow[h * 5]     = f2bf(e0 * inv);
            prow[h * 5 + 1] = f2bf(e1 * inv);
            prow[h * 5 + 2] = f2bf(e2 * inv);
            prow[h * 5 + 3] = f2bf(e3 * inv);
            prow[h * 5 + 4] = f2bf(e4 * inv);
        }
#pragma unroll
        for (int i = 40; i < 64; i++) prow[i] = 0;
#pragma unroll
        for (int s = 0; s < 8; s++)
            *(u16x8*)&As[rr * 64 + s * 8] = *(u16x8*)&prow[s * 8];
    }
    for (int i = t; i < 1024; i += 512) {
        int r = i >> 3, seg = i & 7;
        *(u16x8*)&Bs[r * 64 + seg * 8] =
            *(const u16x8*)&vob[((size_t)b * 512 + nh * 128 + r) * 64 + seg * 8];
    }
    __syncthreads();

    const int wm3 = (wave >> 1) * 64, wn3 = (wave & 1) * 64;
    const int lr = lane & 15, lh = lane >> 4;
    f32x4 acc[4][4] = {};
#pragma unroll
    for (int kk = 0; kk < 2; kk++) {
        bf16x8 af[4], bfr[4];
#pragma unroll
        for (int mi = 0; mi < 4; mi++)
            af[mi] = *(const bf16x8*)&As[(wm3 + mi * 16 + lr) * 64 + kk * 32 + lh * 8];
#pragma unroll
        for (int ni = 0; ni < 4; ni++)
            bfr[ni] = *(const bf16x8*)&Bs[(wn3 + ni * 16 + lr) * 64 + kk * 32 + lh * 8];
#pragma unroll
        for (int mi = 0; mi < 4; mi++)
#pragma unroll
            for (int ni = 0; ni < 4; ni++)
                acc[mi][ni] = __builtin_amdgcn_mfma_f32_16x16x32_bf16(
                    af[mi], bfr[ni], acc[mi][ni], 0, 0, 0);
    }

    const size_t obase = ((size_t)bt * 257 + 1) * 512 + nh * 128;
#pragma unroll
    for (int mi = 0; mi < 4; mi++)
#pragma unroll
        for (int ni = 0; ni < 4; ni++)
#pragma unroll
            for (int r2 = 0; r2 < 4; r2++) {
                int row = wm3 + mi * 16 + lh * 4 + r2;          // 0..255
                int col = wn3 + ni * 16 + lr;                    // 0..127
                out[obase + (size_t)row * 512 + col] = acc[mi][ni][r2] + bo[nh * 128 + col];
            }
}

extern "C" void kernel_launch(void* const* d_in, const int* in_sizes, int n_in,
                              void* d_out, int out_size, void* d_ws, size_t ws_size,
                              hipStream_t stream) {
    const float* x    = (const float*)d_in[0];  // (160,257,512) f32
    const float* mask = (const float*)d_in[1];  // (160,256) f32
    const float* Wv   = (const float*)d_in[2];  // (512,1536) f32
    const float* Wa   = (const float*)d_in[3];  // (512,1536) f32
    const float* Wo   = (const float*)d_in[4];  // (512,512) f32
    const float* bo   = (const float*)d_in[5];  // (512,) f32
    float* out = (float*)d_out;

    char* ws = (char*)d_ws;
    u16*   xb      = (u16*)(ws);                  // 42,106,880
    u16*   WvTv    = (u16*)(ws + 42106880);       //    524,288
    u16*   WaT     = (u16*)(ws + 42631168);       //  1,572,864
    u16*   WoT     = (u16*)(ws + 44204032);       //    524,288
    u16*   aqkv    = (u16*)(ws + 44728320);       //    491,520
    u16*   wcomb   = (u16*)(ws + 45219840);       //  8,388,608  [32][256][512] bf16
    u16*   vv      = (u16*)(ws + 53608448);       // 41,943,040  [40960][512] bf16
    float* vascore = (float*)(ws + 95551488);     //  6,553,600  [40960][40] f32
    float* pglob   = (float*)(ws + 102105088);    //  6,553,600  [1280][1280] f32
    u16*   catA    = (u16*)(ws + 108658688);      //  1,310,720  [160][512] bf16 (padded)
    u16*   vob     = (u16*)(ws + 109969408);      //  2,097,152  [32][512][64] bf16 -> ~112 MB

    prep<<<dim3(10600), 256, 0, stream>>>(x, Wv, Wa, Wo, xb, WvTv, WaT, WoT);

    // a_qkv = A @ Wa_qkv (MFMA path — fast for K=512)
    gemm_k<2, 0><<<dim3(12, 2), 256, 0, stream>>>(xb, WaT, aqkv, nullptr, 160, 1536, 512);

    // combined vectors for scores and fused out-proj (one launch)
    wbuild_all<<<dim3(384), 512, 0, stream>>>(Wv, Wo, aqkv, wcomb, vob);

    // fused: vv = V @ Wv_v  AND  raw scores (av -> pglob, va -> vascore)
    gemm_vs<<<dim3(480), 1024, 0, stream>>>(xb, WvTv, wcomb, vv, pglob, vascore);

    // merged: av softmax+PV -> catA  AND  va softmax + p@vob -> out V rows
    attn_out<<<dim3(896), 512, 0, stream>>>(vv, pglob, catA, vascore, mask, vob, bo, out);

    // out A rows = catA @ Wo + bo  (M=160, out row map r*257)
    gemm_k<0, 2><<<dim3(4, 2), 256, 0, stream>>>(catA, WoT, out, bo, 160, 512, 512);
}